// Round 9
// baseline (24349.329 us; speedup 1.0000x reference)
//
#include <hip/hip_runtime.h>

constexpr int Bb = 4, Ss = 2048, Hh = 2048;
constexpr int GHh = 1024, G3 = 3072;
constexpr int NTOK = 8192;
constexpr int NWG = 64;                        // scan workgroups (16 outputs each)

// Workspace layout (float offsets)
constexpr size_t WSO_XI = 0;                                  // 8192*3072
constexpr size_t WSO_YS = WSO_XI + (size_t)NTOK * G3;         // 8192*1024 (f32 routing)
constexpr size_t WSO_WN = WSO_YS + (size_t)NTOK * GHh;        // 1024*2048
constexpr size_t WSO_PENTOK = WSO_WN + (size_t)GHh * Hh;      // 8192
constexpr size_t WSO_PART = WSO_PENTOK + NTOK;                // 256
constexpr size_t WSO_PENS = WSO_PART + 256;                   // 1 (+pad)
constexpr size_t WSO_FLAGS = WSO_PENS + 16;                   // NWG ints (8B-aligned)

// Output layout (float offsets, concatenated reference outputs)
constexpr size_t OUT_MULT = 0;                                // 8192*2
constexpr size_t OUT_SEL = 16384;                             // 8192*2
constexpr size_t OUT_ELOG = 32768;                            // 8192*1024
constexpr size_t OUT_HLAST = OUT_ELOG + (size_t)NTOK * GHh;   // 4096
constexpr size_t OUT_PEN = OUT_HLAST + 4096;                  // 1
constexpr size_t OUT_COS = OUT_PEN + 1;                       // 8192*8
constexpr size_t OUT_ELOSS = OUT_COS + (size_t)NTOK * 8;      // 1

__device__ __forceinline__ float wred(float v) {
#pragma unroll
  for (int o = 32; o > 0; o >>= 1) v += __shfl_xor(v, o, 64);
  return v;
}

// ---------------- f32 GEMM: C[M][N] = A[M][K] @ W[N][K]^T ----------------
__global__ __launch_bounds__(256)
void gemm_nt(const float* __restrict__ A, const float* __restrict__ W,
             float* __restrict__ C, int M, int N, int K) {
  __shared__ float As[16][132];
  __shared__ float Ws[16][132];
  const int tid = threadIdx.x;
  const int m0 = blockIdx.x * 128, n0 = blockIdx.y * 128;
  const int tx = tid & 15, ty = tid >> 4;
  float acc[8][8];
#pragma unroll
  for (int i = 0; i < 8; ++i)
#pragma unroll
    for (int j = 0; j < 8; ++j) acc[i][j] = 0.f;

  for (int kt = 0; kt < K; kt += 16) {
#pragma unroll
    for (int li = tid; li < 512; li += 256) {
      const int r = li >> 2, kq = li & 3;
      const float4 av = *reinterpret_cast<const float4*>(&A[(size_t)(m0 + r) * K + kt + kq * 4]);
      As[kq * 4 + 0][r] = av.x; As[kq * 4 + 1][r] = av.y;
      As[kq * 4 + 2][r] = av.z; As[kq * 4 + 3][r] = av.w;
      const float4 wv = *reinterpret_cast<const float4*>(&W[(size_t)(n0 + r) * K + kt + kq * 4]);
      Ws[kq * 4 + 0][r] = wv.x; Ws[kq * 4 + 1][r] = wv.y;
      Ws[kq * 4 + 2][r] = wv.z; Ws[kq * 4 + 3][r] = wv.w;
    }
    __syncthreads();
#pragma unroll
    for (int k = 0; k < 16; ++k) {
      const float4 a0 = *reinterpret_cast<const float4*>(&As[k][ty * 8]);
      const float4 a1 = *reinterpret_cast<const float4*>(&As[k][ty * 8 + 4]);
      const float4 w0 = *reinterpret_cast<const float4*>(&Ws[k][tx * 8]);
      const float4 w1 = *reinterpret_cast<const float4*>(&Ws[k][tx * 8 + 4]);
      const float a[8] = {a0.x, a0.y, a0.z, a0.w, a1.x, a1.y, a1.z, a1.w};
      const float w[8] = {w0.x, w0.y, w0.z, w0.w, w1.x, w1.y, w1.z, w1.w};
#pragma unroll
      for (int i = 0; i < 8; ++i)
#pragma unroll
        for (int j = 0; j < 8; ++j) acc[i][j] += a[i] * w[j];
    }
    __syncthreads();
  }
#pragma unroll
  for (int i = 0; i < 8; ++i) {
    const size_t row = (size_t)(m0 + ty * 8 + i);
    float4 v0 = {acc[i][0], acc[i][1], acc[i][2], acc[i][3]};
    float4 v1 = {acc[i][4], acc[i][5], acc[i][6], acc[i][7]};
    *reinterpret_cast<float4*>(&C[row * N + n0 + tx * 8]) = v0;
    *reinterpret_cast<float4*>(&C[row * N + n0 + tx * 8 + 4]) = v1;
  }
}

// ---- persistent GRU scan, 64 WGs: reg-resident weights, fence-free flag handoff ----
// Protocol (validated r6): finalize lanes sc1-store h into ys; __syncthreads drains
// vmcnt(0) per wave (stores acked at coherence point); tid0 sc1-stores flags[wg]=t+1.
// Consumers relaxed-poll the 64 flags (light, 256B), then sc1-load h.
__global__ __launch_bounds__(256, 1)
void gru_scan(const float* __restrict__ xi, const float* __restrict__ whh,
              const float* __restrict__ h0, float* __restrict__ ys,
              float* __restrict__ hlast, int* __restrict__ flags) {
  __shared__ float hs[Bb * GHh];               // 16 KB: h_{t-1} staged
  const int wg = blockIdx.x, tid = threadIdx.x;
  const int gl = tid >> 4, kc = tid & 15;      // gl 0..15 (g within WG), kc 0..15 (k chunk)
  const int g = wg * 16 + gl;                  // output index 0..1023

  // Weight slice in registers: 3 gates x 16 float4 (192 VGPR); k = kc*4 + i*64
  float4 w[3][16];
#pragma unroll
  for (int gate = 0; gate < 3; ++gate)
#pragma unroll
    for (int i = 0; i < 16; ++i)
      w[gate][i] = *reinterpret_cast<const float4*>(
          &whh[((size_t)gate * GHh + g) * GHh + kc * 4 + i * 64]);

  for (int t = 0; t < Ss; ++t) {
    // xi prefetch for finalize lanes (kc==0): 3 gates x 4 batches
    float xg[3][4];
    if (kc == 0) {
#pragma unroll
      for (int b = 0; b < 4; ++b) {
        const size_t base = (size_t)(b * Ss + t) * G3 + g;
        xg[0][b] = xi[base]; xg[1][b] = xi[base + GHh]; xg[2][b] = xi[base + 2 * GHh];
      }
    }

    if (t > 0) {
      // ---- light poll: 64 flags as 32 u64, wave 0 only ----
      if (tid < 64) {
        const unsigned long long* f64p = reinterpret_cast<const unsigned long long*>(flags);
        int guard = 0;
        for (;;) {
          bool ok = true;
          if (tid < 32) {
            const unsigned long long v =
                __hip_atomic_load(&f64p[tid], __ATOMIC_RELAXED, __HIP_MEMORY_SCOPE_AGENT);
            ok = ((int)(v & 0xffffffffull) >= t) && ((int)(v >> 32) >= t);
          }
          if (__all(ok)) break;
          if (++guard > 2000000) break;        // safety: garbage beats a hung GPU
          __builtin_amdgcn_s_sleep(2);
        }
      }
      __syncthreads();
      // ---- stage h_{t-1} via coherent b64 loads ----
#pragma unroll
      for (int u = 0; u < 8; ++u) {
        const int p = u * 256 + tid;           // pair index 0..2047
        const int b = p >> 9, off = (p << 1) & 1023;
        const unsigned long long hv = __hip_atomic_load(
            reinterpret_cast<const unsigned long long*>(
                &ys[((size_t)(b * Ss + (t - 1)) << 10) + off]),
            __ATOMIC_RELAXED, __HIP_MEMORY_SCOPE_AGENT);
        *reinterpret_cast<unsigned long long*>(&hs[p * 2]) = hv;
      }
    } else {
#pragma unroll
      for (int u = 0; u < 4; ++u) {
        const int idx = u * 1024 + tid * 4;
        *reinterpret_cast<float4*>(&hs[idx]) = *reinterpret_cast<const float4*>(&h0[idx]);
      }
    }
    __syncthreads();                           // staging complete before compute

    // ---- partial dots: thread (gl,kc) covers k = kc*4 + i*64 ----
    float acc[3][4];
#pragma unroll
    for (int gate = 0; gate < 3; ++gate)
#pragma unroll
      for (int b = 0; b < 4; ++b) acc[gate][b] = 0.f;
#pragma unroll
    for (int i = 0; i < 16; ++i) {
      const int k = kc * 4 + i * 64;
#pragma unroll
      for (int b = 0; b < 4; ++b) {
        const float4 hv = *reinterpret_cast<const float4*>(&hs[b * GHh + k]);
        acc[0][b] += w[0][i].x * hv.x + w[0][i].y * hv.y + w[0][i].z * hv.z + w[0][i].w * hv.w;
        acc[1][b] += w[1][i].x * hv.x + w[1][i].y * hv.y + w[1][i].z * hv.z + w[1][i].w * hv.w;
        acc[2][b] += w[2][i].x * hv.x + w[2][i].y * hv.y + w[2][i].z * hv.z + w[2][i].w * hv.w;
      }
    }
    // ---- 16-lane shuffle reduction within each kc group ----
#pragma unroll
    for (int o = 1; o < 16; o <<= 1) {
#pragma unroll
      for (int gate = 0; gate < 3; ++gate)
#pragma unroll
        for (int b = 0; b < 4; ++b)
          acc[gate][b] += __shfl_xor(acc[gate][b], o, 64);
    }
    if (kc == 0) {
#pragma unroll
      for (int b = 0; b < 4; ++b) {
        const float rg = 1.f / (1.f + __expf(-(xg[0][b] + acc[0][b])));
        const float zg = 1.f / (1.f + __expf(-(xg[1][b] + acc[1][b])));
        const float ng = tanhf(xg[2][b] + rg * acc[2][b]);
        const float hnew = (1.f - zg) * ng + zg * hs[b * GHh + g];
        __hip_atomic_store(&ys[((size_t)(b * Ss + t) << 10) + g], hnew,
                           __ATOMIC_RELAXED, __HIP_MEMORY_SCOPE_AGENT);
        if (t == Ss - 1) hlast[b * GHh + g] = hnew;
      }
    }
    __syncthreads();   // each wave drains vmcnt(0) before s_barrier -> h stores acked
    if (tid == 0)
      __hip_atomic_store(&flags[wg], t + 1, __ATOMIC_RELAXED, __HIP_MEMORY_SCOPE_AGENT);
  }
}

// ---------------- per-token: l2norm, gram penalty, cosine ----------------
__global__ __launch_bounds__(256)
void token_kernel(const float* __restrict__ ys, const float* __restrict__ elog,
                  float* __restrict__ cosout, float* __restrict__ pen_tok) {
  const int lane = threadIdx.x & 63;
  const int tok = blockIdx.x * 4 + (threadIdx.x >> 6);
  const float* rp = ys + (size_t)tok * GHh;
  const float* ep = elog + (size_t)tok * GHh;
  float rr[8][2], el[8][2];
#pragma unroll
  for (int e = 0; e < 8; ++e) {
    rr[e][0] = rp[e * 128 + lane]; rr[e][1] = rp[e * 128 + 64 + lane];
    el[e][0] = ep[e * 128 + lane]; el[e][1] = ep[e * 128 + 64 + lane];
  }
#pragma unroll
  for (int e = 0; e < 8; ++e) {
    const float s = wred(rr[e][0] * rr[e][0] + rr[e][1] * rr[e][1]);
    const float inv = 1.f / fmaxf(sqrtf(s), 1e-12f);
    rr[e][0] *= inv; rr[e][1] *= inv;
  }
  float pen = 0.f;
  for (int e = 0; e < 8; ++e) {
    float srow = 0.f;
    for (int f = 0; f < 8; ++f) {
      const float gv = wred(rr[e][0] * rr[f][0] + rr[e][1] * rr[f][1]);
      const float dv = gv - (e == f ? 1.f : 0.f);
      srow += dv * dv;
    }
    pen += srow / fmaxf(srow, 1e-24f);
  }
#pragma unroll
  for (int e = 0; e < 8; ++e) {
    const float dot = wred(el[e][0] * rr[e][0] + el[e][1] * rr[e][1]);
    const float na2 = wred(el[e][0] * el[e][0] + el[e][1] * el[e][1]);
    const float nb2 = wred(rr[e][0] * rr[e][0] + rr[e][1] * rr[e][1]);
    const float cs = dot / (fmaxf(sqrtf(na2), 1e-8f) * fmaxf(sqrtf(nb2), 1e-8f));
    if (lane == e) cosout[(size_t)tok * 8 + e] = 1.f - cs;
  }
  if (lane == 0) pen_tok[tok] = pen;
}

// ---------------- expr_w row-normalize ----------------
__global__ __launch_bounds__(256)
void wn_prep(const float* __restrict__ w, float* __restrict__ wn) {
  const int lane = threadIdx.x & 63;
  const int row = blockIdx.x * 4 + (threadIdx.x >> 6);
  const float* src = w + (size_t)row * Hh;
  float s = 0.f;
  for (int c = lane; c < Hh; c += 64) { const float v = src[c]; s += v * v; }
  s = wred(s);
  const float inv = 1.f / fmaxf(sqrtf(s), 1e-12f);
  float* dst = wn + (size_t)row * Hh;
  for (int c = lane; c < Hh; c += 64) dst[c] = src[c] * inv;
}

// ---------------- gram(wn) orthogonality loss partials ----------------
__global__ __launch_bounds__(256)
void gw_loss(const float* __restrict__ wn, float* __restrict__ partial) {
  __shared__ float As[32][68];
  __shared__ float Bs[32][68];
  __shared__ float rbuf[256];
  const int tid = threadIdx.x;
  const int m0 = blockIdx.x * 64, n0 = blockIdx.y * 64;
  const int tx = tid & 15, ty = tid >> 4;
  float acc[4][4];
#pragma unroll
  for (int i = 0; i < 4; ++i)
#pragma unroll
    for (int j = 0; j < 4; ++j) acc[i][j] = 0.f;

  for (int kt = 0; kt < Hh; kt += 32) {
#pragma unroll
    for (int li = tid; li < 512; li += 256) {
      const int r = li >> 3, kq = li & 7;
      const float4 av = *reinterpret_cast<const float4*>(&wn[(size_t)(m0 + r) * Hh + kt + kq * 4]);
      As[kq * 4 + 0][r] = av.x; As[kq * 4 + 1][r] = av.y;
      As[kq * 4 + 2][r] = av.z; As[kq * 4 + 3][r] = av.w;
      const float4 bv = *reinterpret_cast<const float4*>(&wn[(size_t)(n0 + r) * Hh + kt + kq * 4]);
      Bs[kq * 4 + 0][r] = bv.x; Bs[kq * 4 + 1][r] = bv.y;
      Bs[kq * 4 + 2][r] = bv.z; Bs[kq * 4 + 3][r] = bv.w;
    }
    __syncthreads();
#pragma unroll
    for (int k = 0; k < 32; ++k) {
      const float4 a4 = *reinterpret_cast<const float4*>(&As[k][ty * 4]);
      const float4 b4 = *reinterpret_cast<const float4*>(&Bs[k][tx * 4]);
      const float a[4] = {a4.x, a4.y, a4.z, a4.w};
      const float b[4] = {b4.x, b4.y, b4.z, b4.w};
#pragma unroll
      for (int i = 0; i < 4; ++i)
#pragma unroll
        for (int j = 0; j < 4; ++j) acc[i][j] += a[i] * b[j];
    }
    __syncthreads();
  }
  float local = 0.f;
#pragma unroll
  for (int i = 0; i < 4; ++i)
#pragma unroll
    for (int j = 0; j < 4; ++j) {
      const float d = acc[i][j] - ((m0 + ty * 4 + i) == (n0 + tx * 4 + j) ? 1.f : 0.f);
      local += d * d;
    }
  rbuf[tid] = local;
  __syncthreads();
  for (int o = 128; o > 0; o >>= 1) {
    if (tid < o) rbuf[tid] += rbuf[tid + o];
    __syncthreads();
  }
  if (tid == 0) partial[blockIdx.y * 16 + blockIdx.x] = rbuf[0];
}

// ---------------- scalar reductions (deterministic, fixed order) ----------------
__global__ __launch_bounds__(256)
void scalars_kernel(const float* __restrict__ pen_tok, const float* __restrict__ partial,
                    float* __restrict__ out_pen, float* __restrict__ ws_pen,
                    float* __restrict__ out_eloss) {
  __shared__ float sm[256];
  const int tid = threadIdx.x;
  float s = 0.f;
  for (int i = tid; i < NTOK; i += 256) s += pen_tok[i];
  sm[tid] = s;
  __syncthreads();
  for (int o = 128; o > 0; o >>= 1) {
    if (tid < o) sm[tid] += sm[tid + o];
    __syncthreads();
  }
  if (tid == 0) { const float p = sm[0] / (float)NTOK; out_pen[0] = p; ws_pen[0] = p; }
  __syncthreads();
  sm[tid] = partial[tid];
  __syncthreads();
  for (int o = 128; o > 0; o >>= 1) {
    if (tid < o) sm[tid] += sm[tid + o];
    __syncthreads();
  }
  if (tid == 0) out_eloss[0] = sm[0] / (1024.f * 1024.f);
}

// ---------------- top-k(2) + softmax ----------------
__global__ __launch_bounds__(256)
void topk_kernel(const float* __restrict__ cosf, const float* __restrict__ pens,
                 float* __restrict__ mult, float* __restrict__ sel) {
  const int tok = blockIdx.x * 256 + threadIdx.x;
  const float p = 1.f + pens[0];
  float sc[8];
#pragma unroll
  for (int e = 0; e < 8; ++e) sc[e] = cosf[(size_t)tok * 8 + e] * p;
  int i0 = 0; float v0 = sc[0];
#pragma unroll
  for (int e = 1; e < 8; ++e) if (sc[e] > v0) { v0 = sc[e]; i0 = e; }
  int i1 = -1; float v1 = -3.4e38f;
#pragma unroll
  for (int e = 0; e < 8; ++e) if (e != i0 && sc[e] > v1) { v1 = sc[e]; i1 = e; }
  const float ex = __expf(v1 - v0);
  const float den = 1.f + ex;
  mult[(size_t)tok * 2] = 1.f / den;
  mult[(size_t)tok * 2 + 1] = ex / den;
  sel[(size_t)tok * 2] = (float)i0;
  sel[(size_t)tok * 2 + 1] = (float)i1;
}

extern "C" void kernel_launch(void* const* d_in, const int* in_sizes, int n_in,
                              void* d_out, int out_size, void* d_ws, size_t ws_size,
                              hipStream_t stream) {
  (void)in_sizes; (void)n_in; (void)out_size; (void)ws_size;
  const float* x = (const float*)d_in[0];
  const float* hn = (const float*)d_in[1];
  const float* w_ih = (const float*)d_in[2];
  const float* w_hh = (const float*)d_in[3];
  const float* expr_w = (const float*)d_in[4];
  float* out = (float*)d_out;
  float* ws = (float*)d_ws;

  float* xi = ws + WSO_XI;
  float* ysb = ws + WSO_YS;
  float* wn = ws + WSO_WN;
  float* pen_tok = ws + WSO_PENTOK;
  float* partial = ws + WSO_PART;
  float* pens = ws + WSO_PENS;
  int* flags = (int*)(ws + WSO_FLAGS);

  hipMemsetAsync(flags, 0, NWG * sizeof(int), stream);

  gemm_nt<<<dim3(64, 24), 256, 0, stream>>>(x, w_ih, xi, NTOK, G3, Hh);
  gru_scan<<<dim3(NWG), 256, 0, stream>>>(xi, w_hh, hn, ysb, out + OUT_HLAST, flags);
  gemm_nt<<<dim3(64, 8), 256, 0, stream>>>(x, expr_w, out + OUT_ELOG, NTOK, GHh, Hh);
  wn_prep<<<dim3(256), 256, 0, stream>>>(expr_w, wn);
  gw_loss<<<dim3(16, 16), 256, 0, stream>>>(wn, partial);
  token_kernel<<<dim3(2048), 256, 0, stream>>>(ysb, out + OUT_ELOG, out + OUT_COS, pen_tok);
  scalars_kernel<<<dim3(1), 256, 0, stream>>>(pen_tok, partial, out + OUT_PEN, pens,
                                              out + OUT_ELOSS);
  topk_kernel<<<dim3(32), 256, 0, stream>>>(out + OUT_COS, pens, out + OUT_MULT, out + OUT_SEL);
}

// Round 11
// 18295.587 us; speedup vs baseline: 1.3309x; 1.3309x over previous
//
#include <hip/hip_runtime.h>

constexpr int Bb = 4, Ss = 2048, Hh = 2048;
constexpr int GHh = 1024, G3 = 3072;
constexpr int NTOK = 8192;
constexpr int NWG = 128;

// Workspace layout (float offsets)
constexpr size_t WSO_XI = 0;                                  // 8192*3072
constexpr size_t WSO_YS = WSO_XI + (size_t)NTOK * G3;         // 8192*1024 (f32 routing)
constexpr size_t WSO_WN = WSO_YS + (size_t)NTOK * GHh;        // 1024*2048
constexpr size_t WSO_PENTOK = WSO_WN + (size_t)GHh * Hh;      // 8192
constexpr size_t WSO_PART = WSO_PENTOK + NTOK;                // 256
constexpr size_t WSO_PENS = WSO_PART + 256;                   // 1 (+pad)
constexpr size_t WSO_TAG = WSO_PENS + 16;                     // 2*4096 u64 = 16384 floats

// Output layout (float offsets, concatenated reference outputs)
constexpr size_t OUT_MULT = 0;                                // 8192*2
constexpr size_t OUT_SEL = 16384;                             // 8192*2
constexpr size_t OUT_ELOG = 32768;                            // 8192*1024
constexpr size_t OUT_HLAST = OUT_ELOG + (size_t)NTOK * GHh;   // 4096
constexpr size_t OUT_PEN = OUT_HLAST + 4096;                  // 1
constexpr size_t OUT_COS = OUT_PEN + 1;                       // 8192*8
constexpr size_t OUT_ELOSS = OUT_COS + (size_t)NTOK * 8;      // 1

__device__ __forceinline__ float wred(float v) {
#pragma unroll
  for (int o = 32; o > 0; o >>= 1) v += __shfl_xor(v, o, 64);
  return v;
}

// ---------------- f32 GEMM: C[M][N] = A[M][K] @ W[N][K]^T ----------------
__global__ __launch_bounds__(256)
void gemm_nt(const float* __restrict__ A, const float* __restrict__ W,
             float* __restrict__ C, int M, int N, int K) {
  __shared__ float As[16][132];
  __shared__ float Ws[16][132];
  const int tid = threadIdx.x;
  const int m0 = blockIdx.x * 128, n0 = blockIdx.y * 128;
  const int tx = tid & 15, ty = tid >> 4;
  float acc[8][8];
#pragma unroll
  for (int i = 0; i < 8; ++i)
#pragma unroll
    for (int j = 0; j < 8; ++j) acc[i][j] = 0.f;

  for (int kt = 0; kt < K; kt += 16) {
#pragma unroll
    for (int li = tid; li < 512; li += 256) {
      const int r = li >> 2, kq = li & 3;
      const float4 av = *reinterpret_cast<const float4*>(&A[(size_t)(m0 + r) * K + kt + kq * 4]);
      As[kq * 4 + 0][r] = av.x; As[kq * 4 + 1][r] = av.y;
      As[kq * 4 + 2][r] = av.z; As[kq * 4 + 3][r] = av.w;
      const float4 wv = *reinterpret_cast<const float4*>(&W[(size_t)(n0 + r) * K + kt + kq * 4]);
      Ws[kq * 4 + 0][r] = wv.x; Ws[kq * 4 + 1][r] = wv.y;
      Ws[kq * 4 + 2][r] = wv.z; Ws[kq * 4 + 3][r] = wv.w;
    }
    __syncthreads();
#pragma unroll
    for (int k = 0; k < 16; ++k) {
      const float4 a0 = *reinterpret_cast<const float4*>(&As[k][ty * 8]);
      const float4 a1 = *reinterpret_cast<const float4*>(&As[k][ty * 8 + 4]);
      const float4 w0 = *reinterpret_cast<const float4*>(&Ws[k][tx * 8]);
      const float4 w1 = *reinterpret_cast<const float4*>(&Ws[k][tx * 8 + 4]);
      const float a[8] = {a0.x, a0.y, a0.z, a0.w, a1.x, a1.y, a1.z, a1.w};
      const float w[8] = {w0.x, w0.y, w0.z, w0.w, w1.x, w1.y, w1.z, w1.w};
#pragma unroll
      for (int i = 0; i < 8; ++i)
#pragma unroll
        for (int j = 0; j < 8; ++j) acc[i][j] += a[i] * w[j];
    }
    __syncthreads();
  }
#pragma unroll
  for (int i = 0; i < 8; ++i) {
    const size_t row = (size_t)(m0 + ty * 8 + i);
    float4 v0 = {acc[i][0], acc[i][1], acc[i][2], acc[i][3]};
    float4 v1 = {acc[i][4], acc[i][5], acc[i][6], acc[i][7]};
    *reinterpret_cast<float4*>(&C[row * N + n0 + tx * 8]) = v0;
    *reinterpret_cast<float4*>(&C[row * N + n0 + tx * 8 + 4]) = v1;
  }
}

// ---- persistent GRU scan: tag-embedded handoff + SELECTIVE retry ----
// tagBuf[parity][b*1024+g] : u64 = (step_tag << 32) | f32_bits(h)
// producer at iter t stores tag=t+1 into buffer (t+1)&1 (fire-and-forget, no drain).
// consumer at iter t (t>=1) loads buffer t&1; accepts entries with tag>=t;
// retries ONLY the stale ones (16-bit done mask). Parity-overwrite safety: a
// producer can only rewrite buf[p] after observing all tags>=t+1, which implies
// every WG's reads of buf[p] for step t already retired (r7 proof).
__global__ __launch_bounds__(256, 1)
void gru_scan(const float* __restrict__ xi, const float* __restrict__ whh,
              const float* __restrict__ h0, float* __restrict__ ys,
              float* __restrict__ hlast, unsigned long long* __restrict__ tagBuf) {
  __shared__ float hs[Bb * GHh];               // 16 KB: h_{t-1} staged
  const int wg = blockIdx.x, tid = threadIdx.x;
  const int gl = tid >> 5, kc = tid & 31;      // gl 0..7, kc 0..31 (k chunk, half-wave)
  const int g = wg * 8 + gl;                   // output index 0..1023

  // Weight slice in registers: 3 gates x 8 float4 (96 VGPR; r6-proven resident)
  float4 w[3][8];
#pragma unroll
  for (int gate = 0; gate < 3; ++gate)
#pragma unroll
    for (int i = 0; i < 8; ++i)
      w[gate][i] = *reinterpret_cast<const float4*>(
          &whh[((size_t)gate * GHh + g) * GHh + kc * 4 + i * 128]);

  for (int t = 0; t < Ss; ++t) {
    // xi prefetch for finalize lanes (kc<4 -> b=kc); overlaps the poll below
    float xr_ = 0.f, xz_ = 0.f, xn_ = 0.f;
    if (kc < 4) {
      const size_t base = (size_t)(kc * Ss + t) * G3 + g;
      xr_ = xi[base]; xz_ = xi[base + GHh]; xn_ = xi[base + 2 * GHh];
    }

    if (t > 0) {
      // ---- stage+poll fused: load tagged h, retry only stale entries ----
      const unsigned long long* src = tagBuf + (size_t)(t & 1) * 4096;
      unsigned done = 0;
      int guard = 0;
      while (done != 0xffffu) {
#pragma unroll
        for (int u = 0; u < 16; ++u) {
          if (!(done & (1u << u))) {
            const int e = u * 256 + tid;
            const unsigned long long v =
                __hip_atomic_load(&src[e], __ATOMIC_RELAXED, __HIP_MEMORY_SCOPE_AGENT);
            if ((int)(unsigned)(v >> 32) >= t) {
              hs[e] = __uint_as_float((unsigned)v);
              done |= (1u << u);
            }
          }
        }
        if (++guard > 1000000) break;          // safety: garbage beats a hung GPU
      }
    } else {
#pragma unroll
      for (int u = 0; u < 4; ++u) {
        const int idx = u * 1024 + tid * 4;
        *reinterpret_cast<float4*>(&hs[idx]) = *reinterpret_cast<const float4*>(&h0[idx]);
      }
    }
    __syncthreads();                           // staging complete before compute

    // ---- partial dots: thread (gl,kc) covers k = kc*4 + i*128 ----
    float acc[3][4];
#pragma unroll
    for (int gate = 0; gate < 3; ++gate)
#pragma unroll
      for (int b = 0; b < 4; ++b) acc[gate][b] = 0.f;
#pragma unroll
    for (int i = 0; i < 8; ++i) {
      const int k = kc * 4 + i * 128;
#pragma unroll
      for (int b = 0; b < 4; ++b) {
        const float4 hv = *reinterpret_cast<const float4*>(&hs[b * GHh + k]);
        acc[0][b] += w[0][i].x * hv.x + w[0][i].y * hv.y + w[0][i].z * hv.z + w[0][i].w * hv.w;
        acc[1][b] += w[1][i].x * hv.x + w[1][i].y * hv.y + w[1][i].z * hv.z + w[1][i].w * hv.w;
        acc[2][b] += w[2][i].x * hv.x + w[2][i].y * hv.y + w[2][i].z * hv.z + w[2][i].w * hv.w;
      }
    }
    // ---- half-wave (32-lane) shuffle reduction; kc group shares gl ----
#pragma unroll
    for (int o = 1; o < 32; o <<= 1) {
#pragma unroll
      for (int gate = 0; gate < 3; ++gate)
#pragma unroll
        for (int b = 0; b < 4; ++b)
          acc[gate][b] += __shfl_xor(acc[gate][b], o, 64);
    }
    if (kc < 4) {
      const int b = kc;
      const float rg = 1.f / (1.f + __expf(-(xr_ + acc[0][b])));
      const float zg = 1.f / (1.f + __expf(-(xz_ + acc[1][b])));
      const float ng = tanhf(xn_ + rg * acc[2][b]);
      const float hnew = (1.f - zg) * ng + zg * hs[b * GHh + g];
      ys[((size_t)(b * Ss + t) << 10) + g] = hnew;   // routing history (read post-kernel)
      const unsigned long long pk =
          ((unsigned long long)(unsigned)(t + 1) << 32) | __float_as_uint(hnew);
      __hip_atomic_store(&tagBuf[(size_t)((t + 1) & 1) * 4096 + b * GHh + g], pk,
                         __ATOMIC_RELAXED, __HIP_MEMORY_SCOPE_AGENT);
      if (t == Ss - 1) hlast[b * GHh + g] = hnew;
    }
    __syncthreads();                           // WAR guard: hs reads done before next staging
  }
}

// ---------------- per-token: l2norm, gram penalty, cosine ----------------
__global__ __launch_bounds__(256)
void token_kernel(const float* __restrict__ ys, const float* __restrict__ elog,
                  float* __restrict__ cosout, float* __restrict__ pen_tok) {
  const int lane = threadIdx.x & 63;
  const int tok = blockIdx.x * 4 + (threadIdx.x >> 6);
  const float* rp = ys + (size_t)tok * GHh;
  const float* ep = elog + (size_t)tok * GHh;
  float rr[8][2], el[8][2];
#pragma unroll
  for (int e = 0; e < 8; ++e) {
    rr[e][0] = rp[e * 128 + lane]; rr[e][1] = rp[e * 128 + 64 + lane];
    el[e][0] = ep[e * 128 + lane]; el[e][1] = ep[e * 128 + 64 + lane];
  }
#pragma unroll
  for (int e = 0; e < 8; ++e) {
    const float s = wred(rr[e][0] * rr[e][0] + rr[e][1] * rr[e][1]);
    const float inv = 1.f / fmaxf(sqrtf(s), 1e-12f);
    rr[e][0] *= inv; rr[e][1] *= inv;
  }
  float pen = 0.f;
  for (int e = 0; e < 8; ++e) {
    float srow = 0.f;
    for (int f = 0; f < 8; ++f) {
      const float gv = wred(rr[e][0] * rr[f][0] + rr[e][1] * rr[f][1]);
      const float dv = gv - (e == f ? 1.f : 0.f);
      srow += dv * dv;
    }
    pen += srow / fmaxf(srow, 1e-24f);
  }
#pragma unroll
  for (int e = 0; e < 8; ++e) {
    const float dot = wred(el[e][0] * rr[e][0] + el[e][1] * rr[e][1]);
    const float na2 = wred(el[e][0] * el[e][0] + el[e][1] * el[e][1]);
    const float nb2 = wred(rr[e][0] * rr[e][0] + rr[e][1] * rr[e][1]);
    const float cs = dot / (fmaxf(sqrtf(na2), 1e-8f) * fmaxf(sqrtf(nb2), 1e-8f));
    if (lane == e) cosout[(size_t)tok * 8 + e] = 1.f - cs;
  }
  if (lane == 0) pen_tok[tok] = pen;
}

// ---------------- expr_w row-normalize ----------------
__global__ __launch_bounds__(256)
void wn_prep(const float* __restrict__ w, float* __restrict__ wn) {
  const int lane = threadIdx.x & 63;
  const int row = blockIdx.x * 4 + (threadIdx.x >> 6);
  const float* src = w + (size_t)row * Hh;
  float s = 0.f;
  for (int c = lane; c < Hh; c += 64) { const float v = src[c]; s += v * v; }
  s = wred(s);
  const float inv = 1.f / fmaxf(sqrtf(s), 1e-12f);
  float* dst = wn + (size_t)row * Hh;
  for (int c = lane; c < Hh; c += 64) dst[c] = src[c] * inv;
}

// ---------------- gram(wn) orthogonality loss partials ----------------
__global__ __launch_bounds__(256)
void gw_loss(const float* __restrict__ wn, float* __restrict__ partial) {
  __shared__ float As[32][68];
  __shared__ float Bs[32][68];
  __shared__ float rbuf[256];
  const int tid = threadIdx.x;
  const int m0 = blockIdx.x * 64, n0 = blockIdx.y * 64;
  const int tx = tid & 15, ty = tid >> 4;
  float acc[4][4];
#pragma unroll
  for (int i = 0; i < 4; ++i)
#pragma unroll
    for (int j = 0; j < 4; ++j) acc[i][j] = 0.f;

  for (int kt = 0; kt < Hh; kt += 32) {
#pragma unroll
    for (int li = tid; li < 512; li += 256) {
      const int r = li >> 3, kq = li & 7;
      const float4 av = *reinterpret_cast<const float4*>(&wn[(size_t)(m0 + r) * Hh + kt + kq * 4]);
      As[kq * 4 + 0][r] = av.x; As[kq * 4 + 1][r] = av.y;
      As[kq * 4 + 2][r] = av.z; As[kq * 4 + 3][r] = av.w;
      const float4 bv = *reinterpret_cast<const float4*>(&wn[(size_t)(n0 + r) * Hh + kt + kq * 4]);
      Bs[kq * 4 + 0][r] = bv.x; Bs[kq * 4 + 1][r] = bv.y;
      Bs[kq * 4 + 2][r] = bv.z; Bs[kq * 4 + 3][r] = bv.w;
    }
    __syncthreads();
#pragma unroll
    for (int k = 0; k < 32; ++k) {
      const float4 a4 = *reinterpret_cast<const float4*>(&As[k][ty * 4]);
      const float4 b4 = *reinterpret_cast<const float4*>(&Bs[k][tx * 4]);
      const float a[4] = {a4.x, a4.y, a4.z, a4.w};
      const float b[4] = {b4.x, b4.y, b4.z, b4.w};
#pragma unroll
      for (int i = 0; i < 4; ++i)
#pragma unroll
        for (int j = 0; j < 4; ++j) acc[i][j] += a[i] * b[j];
    }
    __syncthreads();
  }
  float local = 0.f;
#pragma unroll
  for (int i = 0; i < 4; ++i)
#pragma unroll
    for (int j = 0; j < 4; ++j) {
      const float d = acc[i][j] - ((m0 + ty * 4 + i) == (n0 + tx * 4 + j) ? 1.f : 0.f);
      local += d * d;
    }
  rbuf[tid] = local;
  __syncthreads();
  for (int o = 128; o > 0; o >>= 1) {
    if (tid < o) rbuf[tid] += rbuf[tid + o];
    __syncthreads();
  }
  if (tid == 0) partial[blockIdx.y * 16 + blockIdx.x] = rbuf[0];
}

// ---------------- scalar reductions (deterministic, fixed order) ----------------
__global__ __launch_bounds__(256)
void scalars_kernel(const float* __restrict__ pen_tok, const float* __restrict__ partial,
                    float* __restrict__ out_pen, float* __restrict__ ws_pen,
                    float* __restrict__ out_eloss) {
  __shared__ float sm[256];
  const int tid = threadIdx.x;
  float s = 0.f;
  for (int i = tid; i < NTOK; i += 256) s += pen_tok[i];
  sm[tid] = s;
  __syncthreads();
  for (int o = 128; o > 0; o >>= 1) {
    if (tid < o) sm[tid] += sm[tid + o];
    __syncthreads();
  }
  if (tid == 0) { const float p = sm[0] / (float)NTOK; out_pen[0] = p; ws_pen[0] = p; }
  __syncthreads();
  sm[tid] = partial[tid];
  __syncthreads();
  for (int o = 128; o > 0; o >>= 1) {
    if (tid < o) sm[tid] += sm[tid + o];
    __syncthreads();
  }
  if (tid == 0) out_eloss[0] = sm[0] / (1024.f * 1024.f);
}

// ---------------- top-k(2) + softmax ----------------
__global__ __launch_bounds__(256)
void topk_kernel(const float* __restrict__ cosf, const float* __restrict__ pens,
                 float* __restrict__ mult, float* __restrict__ sel) {
  const int tok = blockIdx.x * 256 + threadIdx.x;
  const float p = 1.f + pens[0];
  float sc[8];
#pragma unroll
  for (int e = 0; e < 8; ++e) sc[e] = cosf[(size_t)tok * 8 + e] * p;
  int i0 = 0; float v0 = sc[0];
#pragma unroll
  for (int e = 1; e < 8; ++e) if (sc[e] > v0) { v0 = sc[e]; i0 = e; }
  int i1 = -1; float v1 = -3.4e38f;
#pragma unroll
  for (int e = 0; e < 8; ++e) if (e != i0 && sc[e] > v1) { v1 = sc[e]; i1 = e; }
  const float ex = __expf(v1 - v0);
  const float den = 1.f + ex;
  mult[(size_t)tok * 2] = 1.f / den;
  mult[(size_t)tok * 2 + 1] = ex / den;
  sel[(size_t)tok * 2] = (float)i0;
  sel[(size_t)tok * 2 + 1] = (float)i1;
}

extern "C" void kernel_launch(void* const* d_in, const int* in_sizes, int n_in,
                              void* d_out, int out_size, void* d_ws, size_t ws_size,
                              hipStream_t stream) {
  (void)in_sizes; (void)n_in; (void)out_size; (void)ws_size;
  const float* x = (const float*)d_in[0];
  const float* hn = (const float*)d_in[1];
  const float* w_ih = (const float*)d_in[2];
  const float* w_hh = (const float*)d_in[3];
  const float* expr_w = (const float*)d_in[4];
  float* out = (float*)d_out;
  float* ws = (float*)d_ws;

  float* xi = ws + WSO_XI;
  float* ysb = ws + WSO_YS;
  float* wn = ws + WSO_WN;
  float* pen_tok = ws + WSO_PENTOK;
  float* partial = ws + WSO_PART;
  float* pens = ws + WSO_PENS;
  unsigned long long* tagBuf = (unsigned long long*)(ws + WSO_TAG);

  hipMemsetAsync(tagBuf, 0, 2 * 4096 * sizeof(unsigned long long), stream);

  gemm_nt<<<dim3(64, 24), 256, 0, stream>>>(x, w_ih, xi, NTOK, G3, Hh);
  gru_scan<<<dim3(NWG), 256, 0, stream>>>(xi, w_hh, hn, ysb, out + OUT_HLAST, tagBuf);
  gemm_nt<<<dim3(64, 8), 256, 0, stream>>>(x, expr_w, out + OUT_ELOG, NTOK, GHh, Hh);
  wn_prep<<<dim3(256), 256, 0, stream>>>(expr_w, wn);
  gw_loss<<<dim3(16, 16), 256, 0, stream>>>(wn, partial);
  token_kernel<<<dim3(2048), 256, 0, stream>>>(ysb, out + OUT_ELOG, out + OUT_COS, pen_tok);
  scalars_kernel<<<dim3(1), 256, 0, stream>>>(pen_tok, partial, out + OUT_PEN, pens,
                                              out + OUT_ELOSS);
  topk_kernel<<<dim3(32), 256, 0, stream>>>(out + OUT_COS, pens, out + OUT_MULT, out + OUT_SEL);
}

// Round 12
// 12033.833 us; speedup vs baseline: 2.0234x; 1.5203x over previous
//
#include <hip/hip_runtime.h>

constexpr int Bb = 4, Ss = 2048, Hh = 2048;
constexpr int GHh = 1024, G3 = 3072;
constexpr int NTOK = 8192;

// Workspace layout (float offsets)
constexpr size_t WSO_XI = 0;                                  // 8192*3072
constexpr size_t WSO_YS = WSO_XI + (size_t)NTOK * G3;         // 8192*1024 (f32 routing)
constexpr size_t WSO_WN = WSO_YS + (size_t)NTOK * GHh;        // 1024*2048
constexpr size_t WSO_PENTOK = WSO_WN + (size_t)GHh * Hh;      // 8192
constexpr size_t WSO_PART = WSO_PENTOK + NTOK;                // 256
constexpr size_t WSO_PENS = WSO_PART + 256;                   // 1 (+pad)

// Output layout (float offsets, concatenated reference outputs)
constexpr size_t OUT_MULT = 0;                                // 8192*2
constexpr size_t OUT_SEL = 16384;                             // 8192*2
constexpr size_t OUT_ELOG = 32768;                            // 8192*1024
constexpr size_t OUT_HLAST = OUT_ELOG + (size_t)NTOK * GHh;   // 4096
constexpr size_t OUT_PEN = OUT_HLAST + 4096;                  // 1
constexpr size_t OUT_COS = OUT_PEN + 1;                       // 8192*8
constexpr size_t OUT_ELOSS = OUT_COS + (size_t)NTOK * 8;      // 1

__device__ __forceinline__ float wred(float v) {
#pragma unroll
  for (int o = 32; o > 0; o >>= 1) v += __shfl_xor(v, o, 64);
  return v;
}

// ---------------- f32 GEMM: C[M][N] = A[M][K] @ W[N][K]^T ----------------
__global__ __launch_bounds__(256)
void gemm_nt(const float* __restrict__ A, const float* __restrict__ W,
             float* __restrict__ C, int M, int N, int K) {
  __shared__ float As[16][132];
  __shared__ float Ws[16][132];
  const int tid = threadIdx.x;
  const int m0 = blockIdx.x * 128, n0 = blockIdx.y * 128;
  const int tx = tid & 15, ty = tid >> 4;
  float acc[8][8];
#pragma unroll
  for (int i = 0; i < 8; ++i)
#pragma unroll
    for (int j = 0; j < 8; ++j) acc[i][j] = 0.f;

  for (int kt = 0; kt < K; kt += 16) {
#pragma unroll
    for (int li = tid; li < 512; li += 256) {
      const int r = li >> 2, kq = li & 3;
      const float4 av = *reinterpret_cast<const float4*>(&A[(size_t)(m0 + r) * K + kt + kq * 4]);
      As[kq * 4 + 0][r] = av.x; As[kq * 4 + 1][r] = av.y;
      As[kq * 4 + 2][r] = av.z; As[kq * 4 + 3][r] = av.w;
      const float4 wv = *reinterpret_cast<const float4*>(&W[(size_t)(n0 + r) * K + kt + kq * 4]);
      Ws[kq * 4 + 0][r] = wv.x; Ws[kq * 4 + 1][r] = wv.y;
      Ws[kq * 4 + 2][r] = wv.z; Ws[kq * 4 + 3][r] = wv.w;
    }
    __syncthreads();
#pragma unroll
    for (int k = 0; k < 16; ++k) {
      const float4 a0 = *reinterpret_cast<const float4*>(&As[k][ty * 8]);
      const float4 a1 = *reinterpret_cast<const float4*>(&As[k][ty * 8 + 4]);
      const float4 w0 = *reinterpret_cast<const float4*>(&Ws[k][tx * 8]);
      const float4 w1 = *reinterpret_cast<const float4*>(&Ws[k][tx * 8 + 4]);
      const float a[8] = {a0.x, a0.y, a0.z, a0.w, a1.x, a1.y, a1.z, a1.w};
      const float w[8] = {w0.x, w0.y, w0.z, w0.w, w1.x, w1.y, w1.z, w1.w};
#pragma unroll
      for (int i = 0; i < 8; ++i)
#pragma unroll
        for (int j = 0; j < 8; ++j) acc[i][j] += a[i] * w[j];
    }
    __syncthreads();
  }
#pragma unroll
  for (int i = 0; i < 8; ++i) {
    const size_t row = (size_t)(m0 + ty * 8 + i);
    float4 v0 = {acc[i][0], acc[i][1], acc[i][2], acc[i][3]};
    float4 v1 = {acc[i][4], acc[i][5], acc[i][6], acc[i][7]};
    *reinterpret_cast<float4*>(&C[row * N + n0 + tx * 8]) = v0;
    *reinterpret_cast<float4*>(&C[row * N + n0 + tx * 8 + 4]) = v1;
  }
}

// ---- GRU single step: one graph node per t; kernel boundary = sync + coherence ----
// grid 256 WGs x 256 thr. WG wg owns outputs g in [wg*4, wg*4+4), all 4 batches.
// Thread (gl = tid>>6, lane = tid&63): k = lane*4 + i*256, i<4. 192 FMA/thread.
__global__ __launch_bounds__(256)
void gru_step(const float* __restrict__ xi, const float* __restrict__ whh,
              const float* __restrict__ h0, float* __restrict__ ys,
              float* __restrict__ hlast, int t) {
  __shared__ float hs[Bb * GHh];               // 16 KB
  const int tid = threadIdx.x, wg = blockIdx.x;
  const int gl = tid >> 6, lane = tid & 63;
  const int g = wg * 4 + gl;

  // xi prefetch for finalize lanes (lane<4 -> b=lane)
  float xr_ = 0.f, xz_ = 0.f, xn_ = 0.f;
  if (lane < 4) {
    const size_t base = (size_t)(lane * Ss + t) * G3 + g;
    xr_ = xi[base]; xz_ = xi[base + GHh]; xn_ = xi[base + 2 * GHh];
  }

  // stage h_{t-1}: plain cached loads (previous kernel's writes are visible)
  if (t == 0) {
#pragma unroll
    for (int u = 0; u < 4; ++u) {
      const int idx = u * 1024 + tid * 4;
      *reinterpret_cast<float4*>(&hs[idx]) = *reinterpret_cast<const float4*>(&h0[idx]);
    }
  } else {
#pragma unroll
    for (int b = 0; b < 4; ++b) {
      *reinterpret_cast<float4*>(&hs[b * GHh + tid * 4]) =
          *reinterpret_cast<const float4*>(&ys[((size_t)(b * Ss + (t - 1)) << 10) + tid * 4]);
    }
  }
  __syncthreads();

  float acc[3][4];
#pragma unroll
  for (int gate = 0; gate < 3; ++gate)
#pragma unroll
    for (int b = 0; b < 4; ++b) acc[gate][b] = 0.f;
#pragma unroll
  for (int i = 0; i < 4; ++i) {
    const int k = lane * 4 + i * 256;
    const float4 w0 = *reinterpret_cast<const float4*>(&whh[(size_t)g * GHh + k]);
    const float4 w1 = *reinterpret_cast<const float4*>(&whh[(size_t)(GHh + g) * GHh + k]);
    const float4 w2 = *reinterpret_cast<const float4*>(&whh[(size_t)(2 * GHh + g) * GHh + k]);
#pragma unroll
    for (int b = 0; b < 4; ++b) {
      const float4 hv = *reinterpret_cast<const float4*>(&hs[b * GHh + k]);
      acc[0][b] += w0.x * hv.x + w0.y * hv.y + w0.z * hv.z + w0.w * hv.w;
      acc[1][b] += w1.x * hv.x + w1.y * hv.y + w1.z * hv.z + w1.w * hv.w;
      acc[2][b] += w2.x * hv.x + w2.y * hv.y + w2.z * hv.z + w2.w * hv.w;
    }
  }
  // full 64-lane butterfly reduction
#pragma unroll
  for (int o = 1; o < 64; o <<= 1) {
#pragma unroll
    for (int gate = 0; gate < 3; ++gate)
#pragma unroll
      for (int b = 0; b < 4; ++b)
        acc[gate][b] += __shfl_xor(acc[gate][b], o, 64);
  }
  if (lane < 4) {
    const int b = lane;
    const float rg = 1.f / (1.f + __expf(-(xr_ + acc[0][b])));
    const float zg = 1.f / (1.f + __expf(-(xz_ + acc[1][b])));
    const float ng = tanhf(xn_ + rg * acc[2][b]);
    const float hnew = (1.f - zg) * ng + zg * hs[b * GHh + g];
    ys[((size_t)(b * Ss + t) << 10) + g] = hnew;
    if (t == Ss - 1) hlast[b * GHh + g] = hnew;
  }
}

// ---------------- per-token: l2norm, gram penalty, cosine ----------------
__global__ __launch_bounds__(256)
void token_kernel(const float* __restrict__ ys, const float* __restrict__ elog,
                  float* __restrict__ cosout, float* __restrict__ pen_tok) {
  const int lane = threadIdx.x & 63;
  const int tok = blockIdx.x * 4 + (threadIdx.x >> 6);
  const float* rp = ys + (size_t)tok * GHh;
  const float* ep = elog + (size_t)tok * GHh;
  float rr[8][2], el[8][2];
#pragma unroll
  for (int e = 0; e < 8; ++e) {
    rr[e][0] = rp[e * 128 + lane]; rr[e][1] = rp[e * 128 + 64 + lane];
    el[e][0] = ep[e * 128 + lane]; el[e][1] = ep[e * 128 + 64 + lane];
  }
#pragma unroll
  for (int e = 0; e < 8; ++e) {
    const float s = wred(rr[e][0] * rr[e][0] + rr[e][1] * rr[e][1]);
    const float inv = 1.f / fmaxf(sqrtf(s), 1e-12f);
    rr[e][0] *= inv; rr[e][1] *= inv;
  }
  float pen = 0.f;
  for (int e = 0; e < 8; ++e) {
    float srow = 0.f;
    for (int f = 0; f < 8; ++f) {
      const float gv = wred(rr[e][0] * rr[f][0] + rr[e][1] * rr[f][1]);
      const float dv = gv - (e == f ? 1.f : 0.f);
      srow += dv * dv;
    }
    pen += srow / fmaxf(srow, 1e-24f);
  }
#pragma unroll
  for (int e = 0; e < 8; ++e) {
    const float dot = wred(el[e][0] * rr[e][0] + el[e][1] * rr[e][1]);
    const float na2 = wred(el[e][0] * el[e][0] + el[e][1] * el[e][1]);
    const float nb2 = wred(rr[e][0] * rr[e][0] + rr[e][1] * rr[e][1]);
    const float cs = dot / (fmaxf(sqrtf(na2), 1e-8f) * fmaxf(sqrtf(nb2), 1e-8f));
    if (lane == e) cosout[(size_t)tok * 8 + e] = 1.f - cs;
  }
  if (lane == 0) pen_tok[tok] = pen;
}

// ---------------- expr_w row-normalize ----------------
__global__ __launch_bounds__(256)
void wn_prep(const float* __restrict__ w, float* __restrict__ wn) {
  const int lane = threadIdx.x & 63;
  const int row = blockIdx.x * 4 + (threadIdx.x >> 6);
  const float* src = w + (size_t)row * Hh;
  float s = 0.f;
  for (int c = lane; c < Hh; c += 64) { const float v = src[c]; s += v * v; }
  s = wred(s);
  const float inv = 1.f / fmaxf(sqrtf(s), 1e-12f);
  float* dst = wn + (size_t)row * Hh;
  for (int c = lane; c < Hh; c += 64) dst[c] = src[c] * inv;
}

// ---------------- gram(wn) orthogonality loss partials ----------------
__global__ __launch_bounds__(256)
void gw_loss(const float* __restrict__ wn, float* __restrict__ partial) {
  __shared__ float As[32][68];
  __shared__ float Bs[32][68];
  __shared__ float rbuf[256];
  const int tid = threadIdx.x;
  const int m0 = blockIdx.x * 64, n0 = blockIdx.y * 64;
  const int tx = tid & 15, ty = tid >> 4;
  float acc[4][4];
#pragma unroll
  for (int i = 0; i < 4; ++i)
#pragma unroll
    for (int j = 0; j < 4; ++j) acc[i][j] = 0.f;

  for (int kt = 0; kt < Hh; kt += 32) {
#pragma unroll
    for (int li = tid; li < 512; li += 256) {
      const int r = li >> 3, kq = li & 7;
      const float4 av = *reinterpret_cast<const float4*>(&wn[(size_t)(m0 + r) * Hh + kt + kq * 4]);
      As[kq * 4 + 0][r] = av.x; As[kq * 4 + 1][r] = av.y;
      As[kq * 4 + 2][r] = av.z; As[kq * 4 + 3][r] = av.w;
      const float4 bv = *reinterpret_cast<const float4*>(&wn[(size_t)(n0 + r) * Hh + kt + kq * 4]);
      Bs[kq * 4 + 0][r] = bv.x; Bs[kq * 4 + 1][r] = bv.y;
      Bs[kq * 4 + 2][r] = bv.z; Bs[kq * 4 + 3][r] = bv.w;
    }
    __syncthreads();
#pragma unroll
    for (int k = 0; k < 32; ++k) {
      const float4 a4 = *reinterpret_cast<const float4*>(&As[k][ty * 4]);
      const float4 b4 = *reinterpret_cast<const float4*>(&Bs[k][tx * 4]);
      const float a[4] = {a4.x, a4.y, a4.z, a4.w};
      const float b[4] = {b4.x, b4.y, b4.z, b4.w};
#pragma unroll
      for (int i = 0; i < 4; ++i)
#pragma unroll
        for (int j = 0; j < 4; ++j) acc[i][j] += a[i] * b[j];
    }
    __syncthreads();
  }
  float local = 0.f;
#pragma unroll
  for (int i = 0; i < 4; ++i)
#pragma unroll
    for (int j = 0; j < 4; ++j) {
      const float d = acc[i][j] - ((m0 + ty * 4 + i) == (n0 + tx * 4 + j) ? 1.f : 0.f);
      local += d * d;
    }
  rbuf[tid] = local;
  __syncthreads();
  for (int o = 128; o > 0; o >>= 1) {
    if (tid < o) rbuf[tid] += rbuf[tid + o];
    __syncthreads();
  }
  if (tid == 0) partial[blockIdx.y * 16 + blockIdx.x] = rbuf[0];
}

// ---------------- scalar reductions (deterministic, fixed order) ----------------
__global__ __launch_bounds__(256)
void scalars_kernel(const float* __restrict__ pen_tok, const float* __restrict__ partial,
                    float* __restrict__ out_pen, float* __restrict__ ws_pen,
                    float* __restrict__ out_eloss) {
  __shared__ float sm[256];
  const int tid = threadIdx.x;
  float s = 0.f;
  for (int i = tid; i < NTOK; i += 256) s += pen_tok[i];
  sm[tid] = s;
  __syncthreads();
  for (int o = 128; o > 0; o >>= 1) {
    if (tid < o) sm[tid] += sm[tid + o];
    __syncthreads();
  }
  if (tid == 0) { const float p = sm[0] / (float)NTOK; out_pen[0] = p; ws_pen[0] = p; }
  __syncthreads();
  sm[tid] = partial[tid];
  __syncthreads();
  for (int o = 128; o > 0; o >>= 1) {
    if (tid < o) sm[tid] += sm[tid + o];
    __syncthreads();
  }
  if (tid == 0) out_eloss[0] = sm[0] / (1024.f * 1024.f);
}

// ---------------- top-k(2) + softmax ----------------
__global__ __launch_bounds__(256)
void topk_kernel(const float* __restrict__ cosf, const float* __restrict__ pens,
                 float* __restrict__ mult, float* __restrict__ sel) {
  const int tok = blockIdx.x * 256 + threadIdx.x;
  const float p = 1.f + pens[0];
  float sc[8];
#pragma unroll
  for (int e = 0; e < 8; ++e) sc[e] = cosf[(size_t)tok * 8 + e] * p;
  int i0 = 0; float v0 = sc[0];
#pragma unroll
  for (int e = 1; e < 8; ++e) if (sc[e] > v0) { v0 = sc[e]; i0 = e; }
  int i1 = -1; float v1 = -3.4e38f;
#pragma unroll
  for (int e = 0; e < 8; ++e) if (e != i0 && sc[e] > v1) { v1 = sc[e]; i1 = e; }
  const float ex = __expf(v1 - v0);
  const float den = 1.f + ex;
  mult[(size_t)tok * 2] = 1.f / den;
  mult[(size_t)tok * 2 + 1] = ex / den;
  sel[(size_t)tok * 2] = (float)i0;
  sel[(size_t)tok * 2 + 1] = (float)i1;
}

extern "C" void kernel_launch(void* const* d_in, const int* in_sizes, int n_in,
                              void* d_out, int out_size, void* d_ws, size_t ws_size,
                              hipStream_t stream) {
  (void)in_sizes; (void)n_in; (void)out_size; (void)ws_size;
  const float* x = (const float*)d_in[0];
  const float* hn = (const float*)d_in[1];
  const float* w_ih = (const float*)d_in[2];
  const float* w_hh = (const float*)d_in[3];
  const float* expr_w = (const float*)d_in[4];
  float* out = (float*)d_out;
  float* ws = (float*)d_ws;

  float* xi = ws + WSO_XI;
  float* ysb = ws + WSO_YS;
  float* wn = ws + WSO_WN;
  float* pen_tok = ws + WSO_PENTOK;
  float* partial = ws + WSO_PART;
  float* pens = ws + WSO_PENS;

  gemm_nt<<<dim3(64, 24), 256, 0, stream>>>(x, w_ih, xi, NTOK, G3, Hh);
  for (int t = 0; t < Ss; ++t)
    gru_step<<<dim3(256), 256, 0, stream>>>(xi, w_hh, hn, ysb, out + OUT_HLAST, t);
  gemm_nt<<<dim3(64, 8), 256, 0, stream>>>(x, expr_w, out + OUT_ELOG, NTOK, GHh, Hh);
  wn_prep<<<dim3(256), 256, 0, stream>>>(expr_w, wn);
  gw_loss<<<dim3(16, 16), 256, 0, stream>>>(wn, partial);
  token_kernel<<<dim3(2048), 256, 0, stream>>>(ysb, out + OUT_ELOG, out + OUT_COS, pen_tok);
  scalars_kernel<<<dim3(1), 256, 0, stream>>>(pen_tok, partial, out + OUT_PEN, pens,
                                              out + OUT_ELOSS);
  topk_kernel<<<dim3(32), 256, 0, stream>>>(out + OUT_COS, pens, out + OUT_MULT, out + OUT_SEL);
}